// Round 19
// baseline (1206.938 us; speedup 1.0000x reference)
//
#include <hip/hip_runtime.h>
#include <math.h>

typedef __attribute__((ext_vector_type(8))) short short8;
typedef __attribute__((ext_vector_type(8))) _Float16 f16x8;
typedef __attribute__((ext_vector_type(4))) float f32x4;
typedef __attribute__((ext_vector_type(4))) unsigned uint32x4;
typedef __attribute__((ext_vector_type(2))) unsigned uint32x2;

__device__ __forceinline__ void split_f16(float f, unsigned short& h, unsigned short& l){
  _Float16 hh = (_Float16)f;
  _Float16 ll = (_Float16)(f - (float)hh);
  h = __builtin_bit_cast(unsigned short, hh);
  l = __builtin_bit_cast(unsigned short, ll);
}

__device__ __forceinline__ float fsig(float xv){ return 1.f / (1.f + __expf(-xv)); }
__device__ __forceinline__ float ftanh(float xv){ return 1.f - 2.f / (1.f + __expf(2.f * xv)); }

// 256 blocks, 1/CU. grp = bid&7 (XCD hint), slot = bid>>3.
// Phase 1: Z[t=bid] = x_t @ W_ih_t^T in f32 (W_ih streamed once chip-wide).
// Phase 2: BARRIER-FREE recurrence. Each wave is autonomous: polls the 4KB
//   h-tile itself (sc0 local, sticky device fallback), stages into its own
//   private LDS region (in-order LDS per wave => no sync), 32 MFMA, gates,
//   then publishes its own 32B via in-wave shfl-pack + 8B dual stores.
//   No __syncthreads in the 256-step loop. 0xFFFF per-f16 sentinel.
// Tile layout per t: [slot 32][lb 4][jl 16] f16 (4KB).
__global__ __launch_bounds__(256, 1) void lstm_wave(
    const float* __restrict__ x,
    const float* __restrict__ hidden0,
    const float* __restrict__ W_hid,
    const float* __restrict__ b_hid,
    const float* __restrict__ W_ih,
    const float* __restrict__ W_hh,
    const float* __restrict__ b_ih,
    const float* __restrict__ b_hh,
    float* __restrict__ out,
    float* __restrict__ out_h0,
    unsigned* __restrict__ flags,        // [256] one-time init barrier
    float* __restrict__ Zb,              // [256 t][512 j][32 b][4 gates] f32
    unsigned short* __restrict__ hloc,   // [8][256][2048] tiles, plain stores
    unsigned short* __restrict__ hglb)   // [8][256][2048] tiles, sc0sc1 mirror
{
  __shared__ unsigned short hsw[4][4 * 64 * 8];   // per-wave 4KB staging [lb 4][unit 64][8 f16]

  const int tid  = threadIdx.x;
  const int bid  = blockIdx.x;
  const int grp  = bid & 7;
  const int slot = bid >> 3;
  const int lane = tid & 63;
  const int wid  = tid >> 6;               // 0..3 (j-quarter)
  const int m    = lane & 15;
  const int g    = lane >> 4;              // 0..3
  const int J0   = slot * 16;

  const int lbm   = m & 3;                 // batch row this lane's C col maps to
  const int b_o   = grp * 4 + lbm;
  const int j_own = J0 + wid * 4 + g;
  const int R     = (m & 3) * 512 + J0 + wid * 4 + (m >> 2);
  const bool owner = (m < 4);              // unique (b,j) representative

  unsigned short* hlg = hloc + (size_t)grp * 256 * 2048;
  unsigned short* hgg = hglb + (size_t)grp * 256 * 2048;

  // ================= Phase 1: Z producer for t = bid =================
  {
    const int tz = bid;
    const int zb = tid & 31;               // global batch
    const int jq = tid >> 5;               // j-octant
    float xrow[64];
    const float* xp = x + ((size_t)zb * 256 + tz) * 64;
    #pragma unroll
    for (int d4 = 0; d4 < 16; ++d4){
      float4 f = *(const float4*)(xp + d4 * 4);
      xrow[d4*4+0] = f.x; xrow[d4*4+1] = f.y;
      xrow[d4*4+2] = f.z; xrow[d4*4+3] = f.w;
    }
    for (int jj = 0; jj < 64; ++jj){
      int j = jq * 64 + jj;
      uint32x4 zw;
      #pragma unroll
      for (int gate = 0; gate < 4; ++gate){
        const float* wp = W_ih + (size_t)(gate * 512 + j) * 16384 + (size_t)tz * 64;
        float s0 = 0.f, s1 = 0.f, s2 = 0.f, s3 = 0.f;
        #pragma unroll
        for (int d4 = 0; d4 < 16; ++d4){
          float4 w = *(const float4*)(wp + d4 * 4);
          s0 += w.x * xrow[d4*4+0];
          s1 += w.y * xrow[d4*4+1];
          s2 += w.z * xrow[d4*4+2];
          s3 += w.w * xrow[d4*4+3];
        }
        zw[gate] = __builtin_bit_cast(unsigned, (s0 + s1) + (s2 + s3));
      }
      float* zp = Zb + ((size_t)((size_t)tz * 512 + j) * 32 + zb) * 4;
      asm volatile("global_store_dwordx4 %0, %1, off sc0 sc1" :: "v"(zp), "v"(zw) : "memory");
    }
  }

  // ================= own c0/h0: exact f32 dot =================
  float c_state;
  {
    const float* hv = hidden0 + b_o * 64;
    const float* wv = W_hid + j_own * 64;
    float acc = b_hid[j_own];
    #pragma unroll
    for (int d = 0; d < 64; d += 4){
      float4 a = *(const float4*)(hv + d);
      float4 w = *(const float4*)(wv + d);
      acc += a.x*w.x + a.y*w.y + a.z*w.z + a.w*w.w;
    }
    c_state = acc;
    if (owner) out_h0[(size_t)b_o * 512 + j_own] = acc;
    // publish h0 fragment via in-wave shfl pack (lanes 0-3 store 8B each)
    unsigned short hh, ll; split_f16(acc, hh, ll);
    unsigned hb = hh;                      // finite => never 0xFFFF
    unsigned s0 = __shfl(hb, (lane & 3));
    unsigned s1 = __shfl(hb, (lane & 3) + 16);
    unsigned s2 = __shfl(hb, (lane & 3) + 32);
    unsigned s3 = __shfl(hb, (lane & 3) + 48);
    if (lane < 4){
      uint32x2 pk;
      pk[0] = (s0 & 0xFFFFu) | (s1 << 16);
      pk[1] = (s2 & 0xFFFFu) | (s3 << 16);
      size_t off = (size_t)slot * 64 + (size_t)lane * 16 + wid * 4;
      asm volatile("global_store_dwordx2 %0, %1, off"         :: "v"(hlg + off), "v"(pk) : "memory");
      asm volatile("global_store_dwordx2 %0, %1, off sc0 sc1" :: "v"(hgg + off), "v"(pk) : "memory");
    }
  }

  // ================= W_hh fragments -> registers (once) =================
  f16x8 whh_hi[16], whh_lo[16];
  #pragma unroll
  for (int kc = 0; kc < 16; ++kc){
    const float* p = W_hh + (size_t)R * 512 + kc * 32 + g * 8;
    float4 f0 = *(const float4*)p;
    float4 f1 = *(const float4*)(p + 4);
    float fs[8] = {f0.x,f0.y,f0.z,f0.w,f1.x,f1.y,f1.z,f1.w};
    short8 hb8, lb8;
    #pragma unroll
    for (int i = 0; i < 8; ++i){
      unsigned short hh, ll; split_f16(fs[i], hh, ll);
      hb8[i] = (short)hh; lb8[i] = (short)ll;
    }
    whh_hi[kc] = __builtin_bit_cast(f16x8, hb8);
    whh_lo[kc] = __builtin_bit_cast(f16x8, lb8);
  }

  const float bias_i = b_ih[j_own]        + b_hh[j_own];
  const float bias_f = b_ih[512 + j_own]  + b_hh[512 + j_own];
  const float bias_g = b_ih[1024 + j_own] + b_hh[1024 + j_own];
  const float bias_o = b_ih[1536 + j_own] + b_hh[1536 + j_own];

  // ================= one-time barrier: Z + h0 drained & visible =================
  asm volatile("s_waitcnt vmcnt(0)" ::: "memory");
  __syncthreads();
  if (tid == 0){
    unsigned one = 1;
    asm volatile("global_store_dword %0, %1, off sc0 sc1" :: "v"(flags + bid), "v"(one) : "memory");
  }
  {
    const unsigned* fp = flags + lane * 4;
    while (true){
      uint32x4 fv;
      asm volatile("global_load_dwordx4 %0, %1, off sc0 sc1\n\ts_waitcnt vmcnt(0)"
                   : "=v"(fv) : "v"(fp) : "memory");
      unsigned mn0 = fv[0] < fv[1] ? fv[0] : fv[1];
      unsigned mn1 = fv[2] < fv[3] ? fv[2] : fv[3];
      unsigned mn  = mn0 < mn1 ? mn0 : mn1;
      if (__all((int)(mn >= 1u))) break;
      __builtin_amdgcn_s_sleep(1);
    }
  }

  // ================= Phase 2: barrier-free recurrence =================
  bool use_local = true;
  f32x4 axc = {0.f, 0.f, 0.f, 0.f};
  f32x4 zc = *(const f32x4*)(Zb + ((size_t)((size_t)0 * 512 + j_own) * 32 + b_o) * 4);

  unsigned short* myLds = &hsw[wid][0];

  for (int t = 0; t < 256; ++t){
    // ---- prefetch Z(t+1) (plain cached, overlaps poll) ----
    f32x4 zn;
    if (t < 255)
      zn = *(const f32x4*)(Zb + ((size_t)((size_t)(t+1) * 512 + j_own) * 32 + b_o) * 4);

    // ---- poll h(t): THIS WAVE loads the whole 4KB tile (4 dwordx4/lane) ----
    uint32x4 d[4];
    bool got = false;
    if (use_local){
      const unsigned* pb = (const unsigned*)(hlg + (size_t)t * 2048);
      int tries = 0;
      while (tries < 64){
        #pragma unroll
        for (int k = 0; k < 4; ++k){
          const unsigned* p = pb + (size_t)(lane * 4 + k) * 4;
          asm volatile("global_load_dwordx4 %0, %1, off sc0" : "=v"(d[k]) : "v"(p));
        }
        asm volatile("s_waitcnt vmcnt(0)" ::: "memory");
        __builtin_amdgcn_sched_barrier(0);
        int bad = 0;
        #pragma unroll
        for (int k = 0; k < 4; ++k){
          #pragma unroll
          for (int q = 0; q < 4; ++q){
            unsigned w = d[k][q];
            bad |= ((w & 0xFFFFu) == 0xFFFFu) | (w >= 0xFFFF0000u);
          }
        }
        if (!__any(bad)){ got = true; break; }
        __builtin_amdgcn_s_sleep(1);
        ++tries;
      }
      if (!got) use_local = false;       // sticky fallback
    }
    if (!got){
      const unsigned* pb = (const unsigned*)(hgg + (size_t)t * 2048);
      while (true){
        #pragma unroll
        for (int k = 0; k < 4; ++k){
          const unsigned* p = pb + (size_t)(lane * 4 + k) * 4;
          asm volatile("global_load_dwordx4 %0, %1, off sc0 sc1" : "=v"(d[k]) : "v"(p));
        }
        asm volatile("s_waitcnt vmcnt(0)" ::: "memory");
        __builtin_amdgcn_sched_barrier(0);
        int bad = 0;
        #pragma unroll
        for (int k = 0; k < 4; ++k){
          #pragma unroll
          for (int q = 0; q < 4; ++q){
            unsigned w = d[k][q];
            bad |= ((w & 0xFFFFu) == 0xFFFFu) | (w >= 0xFFFF0000u);
          }
        }
        if (!__any(bad)) break;
        __builtin_amdgcn_s_sleep(1);
      }
    }

    // ---- stage into MY wave's LDS region (swizzled); in-order LDS, no sync ----
    #pragma unroll
    for (int k = 0; k < 4; ++k){
      int u     = lane * 4 + k;            // 16B unit 0..255
      int slotu = u >> 3;
      int lb    = (u & 7) >> 1;
      int unit  = slotu * 2 + (u & 1);     // K-unit 0..63
      int usw   = unit ^ lb;
      *(uint32x4*)(myLds + (size_t)(lb * 64 + usw) * 8) = d[k];
    }
    __builtin_amdgcn_sched_barrier(0);     // pin ds_writes before dependent ds_reads

    // ---- h @ W_hh^T via MFMA (2-term W split); B row = m&3 (cols 4-15 dup) ----
    f32x4 acc0 = {0.f,0.f,0.f,0.f}, acc2 = acc0;
    #pragma unroll
    for (int kc = 0; kc < 16; ++kc){
      int us = (kc * 4 + g) ^ lbm;
      f16x8 bhi = __builtin_bit_cast(f16x8, *(const short8*)(myLds + (size_t)(lbm * 64 + us) * 8));
      acc0 = __builtin_amdgcn_mfma_f32_16x16x32_f16(whh_hi[kc], bhi, acc0, 0,0,0);
      acc2 = __builtin_amdgcn_mfma_f32_16x16x32_f16(whh_lo[kc], bhi, acc2, 0,0,0);
    }

    // ---- Z cumsum + gates (every lane computes; duplicates across m-groups) ----
    axc += zc;
    f32x4 pre = acc0 + acc2 + axc;
    float ig = fsig(pre[0] + bias_i);
    float fg = fsig(pre[1] + bias_f);
    float gg = ftanh(pre[2] + bias_g);
    float og = fsig(pre[3] + bias_o);
    c_state = fg * c_state + ig * gg;
    float hval = og * ftanh(c_state);

    // ---- publish this wave's 32B immediately (shfl pack, lanes 0-3) ----
    if (t < 255){
      unsigned short hh, ll; split_f16(hval, hh, ll);
      unsigned hb = hh;                    // finite => never 0xFFFF
      unsigned s0 = __shfl(hb, (lane & 3));
      unsigned s1 = __shfl(hb, (lane & 3) + 16);
      unsigned s2 = __shfl(hb, (lane & 3) + 32);
      unsigned s3 = __shfl(hb, (lane & 3) + 48);
      if (lane < 4){
        uint32x2 pk;
        pk[0] = (s0 & 0xFFFFu) | (s1 << 16);
        pk[1] = (s2 & 0xFFFFu) | (s3 << 16);
        size_t off = (size_t)(t+1) * 2048 + (size_t)slot * 64 + (size_t)lane * 16 + wid * 4;
        asm volatile("global_store_dwordx2 %0, %1, off"         :: "v"(hlg + off), "v"(pk) : "memory");
        asm volatile("global_store_dwordx2 %0, %1, off sc0 sc1" :: "v"(hgg + off), "v"(pk) : "memory");
      }
    }
    if (owner)
      out[((size_t)b_o * 256 + t) * 512 + j_own] = fmaxf(hval, 0.f);

    zc = zn;
  }
}

// ---------------------------------------------------------------------------
extern "C" void kernel_launch(void* const* d_in, const int* in_sizes, int n_in,
                              void* d_out, int out_size, void* d_ws, size_t ws_size,
                              hipStream_t stream) {
  const float* x       = (const float*)d_in[0];
  const float* hidden0 = (const float*)d_in[1];
  const float* W_hid   = (const float*)d_in[2];
  const float* b_hid   = (const float*)d_in[3];
  const float* W_ih    = (const float*)d_in[4];
  const float* W_hh    = (const float*)d_in[5];
  const float* b_ih    = (const float*)d_in[6];
  const float* b_hh    = (const float*)d_in[7];

  float* out    = (float*)d_out;
  float* out_h0 = out + (size_t)32 * 256 * 512;

  char* ws = (char*)d_ws;
  unsigned*       flags = (unsigned*)ws;                            // 1 KB
  float*          Zb    = (float*)(ws + 4096);                      // 64 MB
  unsigned short* hloc  = (unsigned short*)(ws + 4096 + (64u<<20)); // 8 MB
  unsigned short* hglb  = (unsigned short*)(ws + 4096 + (72u<<20)); // 8 MB

  (void)hipMemsetAsync(ws, 0, 4096, stream);
  (void)hipMemsetAsync(hloc, 0xFF, (size_t)8 * 256 * 2048 * 2, stream);
  (void)hipMemsetAsync(hglb, 0xFF, (size_t)8 * 256 * 2048 * 2, stream);

  lstm_wave<<<256, 256, 0, stream>>>(
      x, hidden0, W_hid, b_hid, W_ih, W_hh, b_ih, b_hh,
      out, out_h0, flags, Zb, hloc, hglb);
}

// Round 20
// 484.118 us; speedup vs baseline: 2.4931x; 2.4931x over previous
//
#include <hip/hip_runtime.h>
#include <math.h>

typedef __attribute__((ext_vector_type(8))) short short8;
typedef __attribute__((ext_vector_type(8))) _Float16 f16x8;
typedef __attribute__((ext_vector_type(4))) float f32x4;
typedef __attribute__((ext_vector_type(4))) unsigned uint32x4;

__device__ __forceinline__ void split_f16(float f, unsigned short& h, unsigned short& l){
  _Float16 hh = (_Float16)f;
  _Float16 ll = (_Float16)(f - (float)hh);
  h = __builtin_bit_cast(unsigned short, hh);
  l = __builtin_bit_cast(unsigned short, ll);
}

__device__ __forceinline__ float fsig(float xv){ return 1.f / (1.f + __expf(-xv)); }
__device__ __forceinline__ float ftanh(float xv){ return 1.f - 2.f / (1.f + __expf(2.f * xv)); }

// 256 blocks, 1/CU. grp = bid&7 (XCD hint), slot = bid>>3.
// Group owns batches grp*4..+3; slot owns j = slot*16..+15.
// R14 (in-loop xpart as pacing filler + no Z traffic) composed with
// R18 (packed [slot][lb][jl] h-tile, 8x16B dual stores via LDS pack).
// h exchange: plain->local L2 + sc0sc1->device mirror; consumers poll local
// (sc0), sticky-fallback to mirror. 0xFFFF per-f16 sentinel. G16-safe.
__global__ __launch_bounds__(256, 1) void lstm_grp(
    const float* __restrict__ x,
    const float* __restrict__ hidden0,
    const float* __restrict__ W_hid,
    const float* __restrict__ b_hid,
    const float* __restrict__ W_ih,
    const float* __restrict__ W_hh,
    const float* __restrict__ b_ih,
    const float* __restrict__ b_hh,
    float* __restrict__ out,
    float* __restrict__ out_h0,
    unsigned* __restrict__ flags,        // [256] one-time init barrier
    unsigned short* __restrict__ hloc,   // [8][256][2048] packed tiles, plain
    unsigned short* __restrict__ hglb,   // [8][256][2048] packed tiles, sc0sc1
    unsigned short* __restrict__ xhi,    // [32][256][64] f16 bits
    unsigned short* __restrict__ xlo)
{
  __shared__ unsigned short hsb[2][16 * 64 * 8];   // 2 x 16KB; rows 4..15 garbage
  __shared__ unsigned short hpk[64];               // pack buffer [4 lb][16 jl]

  const int tid  = threadIdx.x;
  const int bid  = blockIdx.x;
  const int grp  = bid & 7;
  const int slot = bid >> 3;
  const int lane = tid & 63;
  const int wid  = tid >> 6;               // 0..3
  const int m    = lane & 15;
  const int g    = lane >> 4;              // 0..3
  const int J0   = slot * 16;
  const int gid  = bid * 256 + tid;

  const int lbm   = m & 3;                 // local batch
  const int b_o   = grp * 4 + lbm;
  const int j_own = J0 + wid * 4 + g;
  const int R     = (m & 3) * 512 + J0 + wid * 4 + (m >> 2);
  const bool owner = (m < 4);

  unsigned short* hlg = hloc + (size_t)grp * 256 * 2048;
  unsigned short* hgg = hglb + (size_t)grp * 256 * 2048;

  // ---------------- init: x -> f16 hi/lo (2 float4 per thread, sc0sc1) ----------------
  {
    const float4* x4 = (const float4*)x;
    float4 f0 = x4[(size_t)gid * 2];
    float4 f1 = x4[(size_t)gid * 2 + 1];
    float fs[8] = {f0.x,f0.y,f0.z,f0.w,f1.x,f1.y,f1.z,f1.w};
    uint32x4 hv4, lv4;
    #pragma unroll
    for (int i = 0; i < 4; ++i){
      unsigned short h0b, l0b, h1b, l1b;
      split_f16(fs[2*i],   h0b, l0b);
      split_f16(fs[2*i+1], h1b, l1b);
      hv4[i] = (unsigned)h0b | ((unsigned)h1b << 16);
      lv4[i] = (unsigned)l0b | ((unsigned)l1b << 16);
    }
    asm volatile("global_store_dwordx4 %0, %1, off sc0 sc1" :: "v"(xhi + (size_t)gid*8), "v"(hv4) : "memory");
    asm volatile("global_store_dwordx4 %0, %1, off sc0 sc1" :: "v"(xlo + (size_t)gid*8), "v"(lv4) : "memory");
  }

  // ---------------- own c0/h0 exact f32; pack h0 into LDS ----------------
  float c_state;
  {
    const float* hv = hidden0 + b_o * 64;
    const float* wv = W_hid + j_own * 64;
    float acc = b_hid[j_own];
    #pragma unroll
    for (int d = 0; d < 64; d += 4){
      float4 a = *(const float4*)(hv + d);
      float4 w = *(const float4*)(wv + d);
      acc += a.x*w.x + a.y*w.y + a.z*w.z + a.w*w.w;
    }
    c_state = acc;
    if (owner){
      out_h0[(size_t)b_o * 512 + j_own] = acc;
      unsigned short hh, ll; split_f16(acc, hh, ll);
      hpk[m * 16 + wid * 4 + g] = hh;      // finite => never 0xFFFF
    }
  }

  // ---------------- W_hh fragments -> registers (once) ----------------
  f16x8 whh_hi[16], whh_lo[16];
  #pragma unroll
  for (int kc = 0; kc < 16; ++kc){
    const float* p = W_hh + (size_t)R * 512 + kc * 32 + g * 8;
    float4 f0 = *(const float4*)p;
    float4 f1 = *(const float4*)(p + 4);
    float fs[8] = {f0.x,f0.y,f0.z,f0.w,f1.x,f1.y,f1.z,f1.w};
    short8 hb8, lb8;
    #pragma unroll
    for (int i = 0; i < 8; ++i){
      unsigned short hh, ll; split_f16(fs[i], hh, ll);
      hb8[i] = (short)hh; lb8[i] = (short)ll;
    }
    whh_hi[kc] = __builtin_bit_cast(f16x8, hb8);
    whh_lo[kc] = __builtin_bit_cast(f16x8, lb8);
  }

  const float bias_i = b_ih[j_own]        + b_hh[j_own];
  const float bias_f = b_ih[512 + j_own]  + b_hh[512 + j_own];
  const float bias_g = b_ih[1024 + j_own] + b_hh[1024 + j_own];
  const float bias_o = b_ih[1536 + j_own] + b_hh[1536 + j_own];

  // ---------------- pack-store h0 tile, then one-time barrier ----------------
  __syncthreads();                        // hpk populated
  if (tid < 8){
    uint32x4 pk = *(const uint32x4*)(hpk + tid * 8);
    unsigned short* d0 = hlg + (size_t)slot * 64 + tid * 8;
    unsigned short* d1 = hgg + (size_t)slot * 64 + tid * 8;
    asm volatile("global_store_dwordx4 %0, %1, off"         :: "v"(d0), "v"(pk) : "memory");
    asm volatile("global_store_dwordx4 %0, %1, off sc0 sc1" :: "v"(d1), "v"(pk) : "memory");
  }
  asm volatile("s_waitcnt vmcnt(0)" ::: "memory");
  __syncthreads();
  if (tid == 0){
    unsigned one = 1;
    asm volatile("global_store_dword %0, %1, off sc0 sc1" :: "v"(flags + bid), "v"(one) : "memory");
  }
  {
    const unsigned* fp = flags + lane * 4;
    while (true){
      uint32x4 fv;
      asm volatile("global_load_dwordx4 %0, %1, off sc0 sc1\n\ts_waitcnt vmcnt(0)"
                   : "=v"(fv) : "v"(fp) : "memory");
      unsigned mn0 = fv[0] < fv[1] ? fv[0] : fv[1];
      unsigned mn1 = fv[2] < fv[3] ? fv[2] : fv[3];
      unsigned mn  = mn0 < mn1 ? mn0 : mn1;
      if (__all((int)(mn >= 1u))) break;
      __builtin_amdgcn_s_sleep(1);
    }
  }

  // ---------------- persistent x@W_ih cumsum (3-term split) ----------------
  f32x4 axc0 = {0.f,0.f,0.f,0.f}, axc1 = axc0, axc2 = axc0;

  auto cvt8 = [](float4 f0, float4 f1, f16x8& hi, f16x8& lo){
    float fs[8] = {f0.x,f0.y,f0.z,f0.w,f1.x,f1.y,f1.z,f1.w};
    short8 hb8, lb8;
    #pragma unroll
    for (int i = 0; i < 8; ++i){
      unsigned short hh, ll; split_f16(fs[i], hh, ll);
      hb8[i] = (short)hh; lb8[i] = (short)ll;
    }
    hi = __builtin_bit_cast(f16x8, hb8);
    lo = __builtin_bit_cast(f16x8, lb8);
  };

  // step-0 x-part (cold, once)
  {
    #pragma unroll
    for (int kc = 0; kc < 2; ++kc){
      const float* p = W_ih + (size_t)R * 16384 + kc * 32 + g * 8;
      f16x8 ahi, alo;
      cvt8(*(const float4*)p, *(const float4*)(p + 4), ahi, alo);
      size_t off = (size_t)b_o * 16384 + kc * 32 + g * 8;
      f16x8 bhi = __builtin_bit_cast(f16x8, *(const short8*)(xhi + off));
      f16x8 blo = __builtin_bit_cast(f16x8, *(const short8*)(xlo + off));
      axc0 = __builtin_amdgcn_mfma_f32_16x16x32_f16(ahi, bhi, axc0, 0,0,0);
      axc1 = __builtin_amdgcn_mfma_f32_16x16x32_f16(ahi, blo, axc1, 0,0,0);
      axc2 = __builtin_amdgcn_mfma_f32_16x16x32_f16(alo, bhi, axc2, 0,0,0);
    }
  }

  // consumer staging decode: thread tid reads 16B at tile + tid*16
  const int sl_src = tid >> 3;
  const int r8     = tid & 7;
  const int lb_c   = r8 >> 1;
  const int u_c    = sl_src * 2 + (r8 & 1);
  const int us_c   = u_c ^ lb_c;
  bool use_local = true;

  for (int t = 0; t < 256; ++t){
    uint32x4 dv;
    bool got = false;

    // ---- poll h(t): block-shared packed tile ----
    if (use_local){
      const unsigned* p = (const unsigned*)(hlg + (size_t)t * 2048) + (size_t)tid * 4;
      int tries = 0;
      while (tries < 64){
        asm volatile("global_load_dwordx4 %0, %1, off sc0\n\ts_waitcnt vmcnt(0)"
                     : "=v"(dv) : "v"(p) : "memory");
        int bad = 0;
        #pragma unroll
        for (int q = 0; q < 4; ++q){
          unsigned w = dv[q];
          bad |= ((w & 0xFFFFu) == 0xFFFFu) | (w >= 0xFFFF0000u);
        }
        if (!__any(bad)){ got = true; break; }
        __builtin_amdgcn_s_sleep(1);
        ++tries;
      }
      if (!got) use_local = false;       // sticky fallback
    }
    if (!got){
      const unsigned* p = (const unsigned*)(hgg + (size_t)t * 2048) + (size_t)tid * 4;
      while (true){
        asm volatile("global_load_dwordx4 %0, %1, off sc0 sc1\n\ts_waitcnt vmcnt(0)"
                     : "=v"(dv) : "v"(p) : "memory");
        int bad = 0;
        #pragma unroll
        for (int q = 0; q < 4; ++q){
          unsigned w = dv[q];
          bad |= ((w & 0xFFFFu) == 0xFFFFu) | (w >= 0xFFFF0000u);
        }
        if (!__any(bad)) break;
        __builtin_amdgcn_s_sleep(1);
      }
    }

    // ---- prefetch W_ih(t+1) + x(t+1) (cached; in flight during stage+MFMA) ----
    float4 w0, w1, w2, w3;
    short8 xh0, xh1, xl0, xl1;
    if (t < 255){
      const float* p = W_ih + (size_t)R * 16384 + (size_t)(t+1) * 64 + g * 8;
      w0 = *(const float4*)p;        w1 = *(const float4*)(p + 4);
      w2 = *(const float4*)(p + 32); w3 = *(const float4*)(p + 36);
      size_t off = ((size_t)b_o * 256 + (size_t)(t+1)) * 64 + g * 8;
      xh0 = *(const short8*)(xhi + off);      xh1 = *(const short8*)(xhi + off + 32);
      xl0 = *(const short8*)(xlo + off);      xl1 = *(const short8*)(xlo + off + 32);
    }

    // ---- stage packed tile -> swizzled LDS rows 0..3, buffer t&1 ----
    *(uint32x4*)(&hsb[t & 1][(size_t)(lb_c * 64 + us_c) * 8]) = dv;
    __syncthreads();   // barrier #1

    // ---- h @ W_hh^T via MFMA (2-term W split, h hi-plane) ----
    f32x4 acc0 = {0.f,0.f,0.f,0.f}, acc2 = acc0;
    {
      const unsigned short* srcH = &hsb[t & 1][0];
      #pragma unroll
      for (int kc = 0; kc < 16; ++kc){
        int us = (kc * 4 + g) ^ (m & 7);
        f16x8 bhi = __builtin_bit_cast(f16x8, *(const short8*)(srcH + (size_t)(m * 64 + us) * 8));
        acc0 = __builtin_amdgcn_mfma_f32_16x16x32_f16(whh_hi[kc], bhi, acc0, 0,0,0);
        acc2 = __builtin_amdgcn_mfma_f32_16x16x32_f16(whh_lo[kc], bhi, acc2, 0,0,0);
      }
    }

    // ---- gates; owners drop h(t+1) into pack LDS ----
    f32x4 pre = acc0 + acc2 + axc0 + axc1 + axc2;
    float ig = fsig(pre[0] + bias_i);
    float fg = fsig(pre[1] + bias_f);
    float gg = ftanh(pre[2] + bias_g);
    float og = fsig(pre[3] + bias_o);
    c_state = fg * c_state + ig * gg;
    float hval = og * ftanh(c_state);

    if (owner){
      unsigned short hh, ll; split_f16(hval, hh, ll);
      hpk[m * 16 + wid * 4 + g] = hh;      // finite => never 0xFFFF
    }
    __syncthreads();   // barrier #2: hpk complete

    // ---- publish 128B (8 x 16B dual stores), earliest possible ----
    if (t < 255 && tid < 8){
      uint32x4 pk = *(const uint32x4*)(hpk + tid * 8);
      unsigned short* d0 = hlg + (size_t)(t+1) * 2048 + (size_t)slot * 64 + tid * 8;
      unsigned short* d1 = hgg + (size_t)(t+1) * 2048 + (size_t)slot * 64 + tid * 8;
      asm volatile("global_store_dwordx4 %0, %1, off"         :: "v"(d0), "v"(pk) : "memory");
      asm volatile("global_store_dwordx4 %0, %1, off sc0 sc1" :: "v"(d1), "v"(pk) : "memory");
    }

    // ---- xpart(t+1): useful filler between publish and next poll ----
    if (t < 255){
      f16x8 ahi0, alo0, ahi1, alo1;
      cvt8(w0, w1, ahi0, alo0);
      cvt8(w2, w3, ahi1, alo1);
      f16x8 bh0 = __builtin_bit_cast(f16x8, xh0), bl0 = __builtin_bit_cast(f16x8, xl0);
      f16x8 bh1 = __builtin_bit_cast(f16x8, xh1), bl1 = __builtin_bit_cast(f16x8, xl1);
      axc0 = __builtin_amdgcn_mfma_f32_16x16x32_f16(ahi0, bh0, axc0, 0,0,0);
      axc1 = __builtin_amdgcn_mfma_f32_16x16x32_f16(ahi0, bl0, axc1, 0,0,0);
      axc2 = __builtin_amdgcn_mfma_f32_16x16x32_f16(alo0, bh0, axc2, 0,0,0);
      axc0 = __builtin_amdgcn_mfma_f32_16x16x32_f16(ahi1, bh1, axc0, 0,0,0);
      axc1 = __builtin_amdgcn_mfma_f32_16x16x32_f16(ahi1, bl1, axc1, 0,0,0);
      axc2 = __builtin_amdgcn_mfma_f32_16x16x32_f16(alo1, bh1, axc2, 0,0,0);
    }

    if (owner)
      out[((size_t)b_o * 256 + t) * 512 + j_own] = fmaxf(hval, 0.f);
  }
}

// ---------------------------------------------------------------------------
extern "C" void kernel_launch(void* const* d_in, const int* in_sizes, int n_in,
                              void* d_out, int out_size, void* d_ws, size_t ws_size,
                              hipStream_t stream) {
  const float* x       = (const float*)d_in[0];
  const float* hidden0 = (const float*)d_in[1];
  const float* W_hid   = (const float*)d_in[2];
  const float* b_hid   = (const float*)d_in[3];
  const float* W_ih    = (const float*)d_in[4];
  const float* W_hh    = (const float*)d_in[5];
  const float* b_ih    = (const float*)d_in[6];
  const float* b_hh    = (const float*)d_in[7];

  float* out    = (float*)d_out;
  float* out_h0 = out + (size_t)32 * 256 * 512;

  char* ws = (char*)d_ws;
  unsigned*       flags = (unsigned*)ws;                            // 1 KB
  unsigned short* xhi   = (unsigned short*)(ws + 4096);             // 1 MB
  unsigned short* xlo   = (unsigned short*)(ws + 4096 + (1<<20));   // 1 MB
  unsigned short* hloc  = (unsigned short*)(ws + 4096 + (2<<20));   // 8 MB
  unsigned short* hglb  = (unsigned short*)(ws + 4096 + (2<<20) + (8<<20)); // 8 MB

  (void)hipMemsetAsync(ws, 0, 4096, stream);
  (void)hipMemsetAsync(hloc, 0xFF, (size_t)8 * 256 * 2048 * 2, stream);
  (void)hipMemsetAsync(hglb, 0xFF, (size_t)8 * 256 * 2048 * 2, stream);

  lstm_grp<<<256, 256, 0, stream>>>(
      x, hidden0, W_hid, b_hid, W_ih, W_hh, b_ih, b_hh,
      out, out_h0, flags, hloc, hglb, xhi, xlo);
}